// Round 8
// baseline (142.960 us; speedup 1.0000x reference)
//
#include <hip/hip_runtime.h>

typedef __bf16 bf16;
typedef __bf16 bf16x4 __attribute__((ext_vector_type(4)));
typedef __bf16 bf16x8 __attribute__((ext_vector_type(8)));
typedef float f32x4 __attribute__((ext_vector_type(4)));
typedef float f32x16 __attribute__((ext_vector_type(16)));

__device__ __forceinline__ f32x4 mfma16(bf16x8 a, bf16x8 b, f32x4 c) {
  return __builtin_amdgcn_mfma_f32_16x16x32_bf16(a, b, c, 0, 0, 0);
}
__device__ __forceinline__ f32x16 mfma32(bf16x8 a, bf16x8 b, f32x16 c) {
  return __builtin_amdgcn_mfma_f32_32x32x16_bf16(a, b, c, 0, 0, 0);
}

__device__ __forceinline__ unsigned pack2(float lo, float hi) {
  unsigned short a = __builtin_bit_cast(unsigned short, (bf16)lo);
  unsigned short b = __builtin_bit_cast(unsigned short, (bf16)hi);
  return ((unsigned)b << 16) | (unsigned)a;
}

// v_permlane32_swap_b32 a, b:  a' = {a.lo, b.lo}, b' = {a.hi, b.hi}
__device__ __forceinline__ void plane32swap(unsigned& a, unsigned& b) {
  asm volatile("v_permlane32_swap_b32 %0, %1" : "+v"(a), "+v"(b));
}

typedef __attribute__((address_space(3))) unsigned int lds_u32;
typedef __attribute__((address_space(1))) unsigned int glb_u32;
// async global->LDS, 16B per lane; LDS dest = base + lane*16 (wave-linear)
__device__ __forceinline__ void gld16(const bf16* g, bf16* l) {
  __builtin_amdgcn_global_load_lds((const glb_u32*)g, (lds_u32*)l, 16, 0, 0);
}

// ---------------------------------------------------------------------------
// prep: fused weight transposes (blocks 0..1023) + RMSNorm (blocks 1024..5119)
// ---------------------------------------------------------------------------
__global__ __launch_bounds__(256)
void prep_kernel(const float* __restrict__ t, const float* __restrict__ f,
                 const float* __restrict__ nw,
                 const float* __restrict__ wq, const float* __restrict__ wkv,
                 const float* __restrict__ wp,
                 bf16* __restrict__ tn, bf16* __restrict__ fn,
                 bf16* __restrict__ wqT, bf16* __restrict__ wkvT,
                 bf16* __restrict__ wpT)
{
  int b = blockIdx.x;
  if (b < 1024) {
    int e = b * 256 + threadIdx.x;   // 0..262143
    const float* src; bf16* dst; int N; int idx;
    if (e < 65536)       { src = wq;  dst = wqT;  N = 256; idx = e; }
    else if (e < 196608) { src = wkv; dst = wkvT; N = 512; idx = e - 65536; }
    else                 { src = wp;  dst = wpT;  N = 256; idx = e - 196608; }
    int k = idx & 255;
    int n = idx >> 8;
    dst[idx] = (bf16)src[(size_t)k * N + n];
    return;
  }
  int wave = threadIdx.x >> 6;
  int lane = threadIdx.x & 63;
  int row = (b - 1024) * 4 + wave;           // 0..16383
  const float* src;
  bf16* dst;
  if (row < 8192) {
    src = t + (size_t)row * 256;
    dst = tn + (size_t)row * 256;
  } else {
    int r2 = row - 8192;
    src = f + (size_t)r2 * 256;
    dst = fn + (size_t)r2 * 256;
  }
  float4 v = reinterpret_cast<const float4*>(src)[lane];
  float ss = v.x * v.x + v.y * v.y + v.z * v.z + v.w * v.w;
  #pragma unroll
  for (int m = 1; m < 64; m <<= 1) ss += __shfl_xor(ss, m);
  float nrm = rsqrtf(ss * (1.0f / 256.0f) + 1e-5f);
  float4 wv = reinterpret_cast<const float4*>(nw)[lane];
  bf16x4 o;
  o[0] = (bf16)(v.x * nrm * wv.x);
  o[1] = (bf16)(v.y * nrm * wv.y);
  o[2] = (bf16)(v.z * nrm * wv.z);
  o[3] = (bf16)(v.w * nrm * wv.w);
  *reinterpret_cast<bf16x4*>(dst + lane * 4) = o;
}

// ---------------------------------------------------------------------------
// GEMM body: out[M=8192, N] = A[8192,256](bf16) @ W[256,N] + bias
// Block tile 64x64, 4 waves in 2x2, each wave 32x32 via 2x2 MFMA frags.
// MODE 0: write Q layout  [b*4+h][t][d]
// MODE 1: write K layout  [b*4+h][f][d]  +  Vt layout [b*4+h][d][f]
// MODE 2: fp32 out = acc + bias + resid(bf16)
// ---------------------------------------------------------------------------
template<int MODE>
__device__ __forceinline__
void gemm_body(int bid, const bf16* __restrict__ A, const bf16* __restrict__ Wt,
               const float* __restrict__ bias, bf16* __restrict__ o0,
               bf16* __restrict__ o1, const bf16* __restrict__ resid,
               float* __restrict__ outf, int N)
{
  int wv = threadIdx.x >> 6;
  int lane = threadIdx.x & 63;
  int lr = lane & 15;
  int lk = (lane >> 4) * 8;
  int wm = wv >> 1, wn = wv & 1;
  int nb = N >> 6;
  int bm = bid / nb;
  int bn = bid - bm * nb;
  int row0 = bm * 64 + wm * 32;
  int col0 = bn * 64 + wn * 32;
  const bf16* Ap = A + (size_t)row0 * 256;
  const bf16* Wp = Wt + (size_t)col0 * 256;

  f32x4 acc[2][2] = {};
  #pragma unroll
  for (int k0 = 0; k0 < 256; k0 += 32) {
    bf16x8 a[2], b[2];
    #pragma unroll
    for (int mi = 0; mi < 2; mi++)
      a[mi] = *reinterpret_cast<const bf16x8*>(Ap + (size_t)(mi * 16 + lr) * 256 + k0 + lk);
    #pragma unroll
    for (int ni = 0; ni < 2; ni++)
      b[ni] = *reinterpret_cast<const bf16x8*>(Wp + (size_t)(ni * 16 + lr) * 256 + k0 + lk);
    #pragma unroll
    for (int mi = 0; mi < 2; mi++)
      #pragma unroll
      for (int ni = 0; ni < 2; ni++)
        acc[mi][ni] = mfma16(a[mi], b[ni], acc[mi][ni]);
  }

  int rb = (lane >> 4) * 4;
  #pragma unroll
  for (int mi = 0; mi < 2; mi++) {
    #pragma unroll
    for (int ni = 0; ni < 2; ni++) {
      int col = col0 + ni * 16 + lr;
      float bv = bias[col];
      #pragma unroll
      for (int r = 0; r < 4; r++) {
        int row = row0 + mi * 16 + rb + r;
        float val = acc[mi][ni][r] + bv;
        if (MODE == 0) {
          int b_ = row >> 12, tt = row & 4095;
          int h = col >> 6, d = col & 63;
          o0[(((size_t)(b_ * 4 + h)) * 4096 + tt) * 64 + d] = (bf16)val;
        } else if (MODE == 1) {
          int b_ = row >> 12, ff = row & 4095;
          if (col < 256) {
            int h = col >> 6, d = col & 63;
            o0[(((size_t)(b_ * 4 + h)) * 4096 + ff) * 64 + d] = (bf16)val;
          } else {
            int c = col - 256;
            int h = c >> 6, d = c & 63;
            o1[(((size_t)(b_ * 4 + h)) * 64 + d) * 4096 + ff] = (bf16)val;
          }
        } else {
          size_t idx = (size_t)row * 256 + col;
          outf[idx] = val + (float)resid[idx];
        }
      }
    }
  }
}

// Fused Q-proj + KV-proj: blocks [0,512) do Q, [512,1536) do KV.
__global__ __launch_bounds__(256)
void gemm_qkv(const bf16* __restrict__ tn, const bf16* __restrict__ fn,
              const bf16* __restrict__ wqT, const bf16* __restrict__ wkvT,
              const float* __restrict__ bq, const float* __restrict__ bkv,
              bf16* __restrict__ q, bf16* __restrict__ k, bf16* __restrict__ vt)
{
  if (blockIdx.x < 512)
    gemm_body<0>(blockIdx.x, tn, wqT, bq, q, nullptr, nullptr, nullptr, 256);
  else
    gemm_body<1>(blockIdx.x - 512, fn, wkvT, bkv, k, vt, nullptr, nullptr, 512);
}

// Output projection + bias + residual.
__global__ __launch_bounds__(256)
void gemm_out(const bf16* __restrict__ ao, const bf16* __restrict__ wpT,
              const float* __restrict__ bp, const bf16* __restrict__ resid,
              float* __restrict__ outf)
{
  gemm_body<2>(blockIdx.x, ao, wpT, bp, nullptr, nullptr, resid, outf, 256);
}

// ---------------------------------------------------------------------------
// Flash attention v6: LDS-shared K/V, triple-buffered, counted vmcnt.
// grid = 1024 blocks: bh = blockIdx&7 (XCD affinity), qb = (blockIdx>>3)&63
// (64 q rows), FQ = blockIdx>>9 (f-half, 2048 f each).
// Block: 4 waves = 2 q-tiles (qi) x 2 f-streams (fh, 1024 f each).
// Per 32-f tile: K/V staged via global_load_lds (16B), 3 LDS bufs/stream,
// staged 2 iterations ahead; in-loop wait is vmcnt(4) (tile-t loads = oldest
// 4 of 8 outstanding) -> no drain stall. Loop: vmcnt(4); barrier; STAGE(t+2);
// compute(t). Wrap-staging keeps the loop uniform. vmcnt(0)+barrier once
// after the loop (stage/merge LDS union).
// Swapped 32x32 MFMA; in-register softmax (log2 units); defer-max THR=8;
// permlane32_swap exchanges; setprio(1) around MFMA clusters.
// ---------------------------------------------------------------------------
__global__ __launch_bounds__(256, 4)
void attn_kernel(const bf16* __restrict__ Q, const bf16* __restrict__ K,
                 const bf16* __restrict__ Vt, bf16* __restrict__ Opart,
                 float2* __restrict__ MLp)
{
  int bh = blockIdx.x & 7;
  int qb = (blockIdx.x >> 3) & 63;
  int FQ = blockIdx.x >> 9;
  int wv = threadIdx.x >> 6;
  int fh = wv >> 1;                // f-stream 0..1
  int qi = wv & 1;                 // q-tile 0..1
  int lane = threadIdx.x & 63;
  int lq = lane & 31;
  int h32 = lane >> 5;

  const bf16* Qb = Q + ((size_t)bh * 4096 + qb * 64 + qi * 32) * 64;
  const bf16* Kb = K + (size_t)bh * 4096 * 64;
  const bf16* Vb = Vt + (size_t)bh * 64 * 4096;

  __shared__ union {
    bf16 stage[2][3][4096];        // [fh][buf][ K' 2048 | V' 2048 ]  48 KB
    struct {
      float o[4][64][33];
      float mm[4][32];
      float lh[4][2][32];
    } mg;
  } lds;

  const float qs = 0.125f * 1.44269504089f;
  bf16x8 qf[4];
  #pragma unroll
  for (int kc = 0; kc < 4; kc++) {
    qf[kc] = *reinterpret_cast<const bf16x8*>(Qb + (size_t)lq * 64 + kc * 16 + h32 * 8);
    #pragma unroll
    for (int i = 0; i < 8; i++) qf[kc][i] = (bf16)((float)qf[kc][i] * qs);
  }

  f32x16 oa[2] = {};
  float m = -3.0e38f, l = 0.f;

  int fbeg = FQ * 2048 + fh * 1024;

  auto STAGE = [&](int buf, int ft) {
    bf16* sb = &lds.stage[fh][buf][0];
    if (qi == 0) {
      #pragma unroll
      for (int j = 0; j < 4; j++) {
        const bf16* src = Kb + (size_t)(ft + lq) * 64 + (j * 2 + h32) * 8;
        gld16(src, sb + j * 512);              // K': dch-major
      }
    } else {
      #pragma unroll
      for (int j = 0; j < 4; j++) {
        const bf16* src = Vb + (size_t)lane * 4096 + ft + j * 8;
        gld16(src, sb + 2048 + j * 512);       // V': fch-major
      }
    }
  };

  // prologue: stage tiles 0 and 1 (8 outstanding gld16 per staging wave)
  STAGE(0, fbeg);
  STAGE(1, fbeg + 32);

  int c = 0;                                   // buf index of tile t
  for (int t = 0; t < 32; ++t) {
    // tile t's 4 loads are the oldest of 8 outstanding -> counted wait
    asm volatile("s_waitcnt vmcnt(4)" ::: "memory");
    __syncthreads();                           // tile t visible; t-1 consumed

    // stage tile t+2 (wrap keeps the loop & vmcnt uniform; wraps unused)
    int tn_ = t + 2;
    int ft = fbeg + (tn_ >= 32 ? tn_ - 32 : tn_) * 32;
    int bnext = c + 2; if (bnext >= 3) bnext -= 3;
    STAGE(bnext, ft);

    const bf16* kb = &lds.stage[fh][c][0];
    const bf16* vb = kb + 2048;

    // S^T (32f x 32q) = K . Q^T   (log2 units)
    f32x16 st = {};
    __builtin_amdgcn_s_setprio(1);
    #pragma unroll
    for (int kc = 0; kc < 4; kc++) {
      bf16x8 kf = *reinterpret_cast<const bf16x8*>(kb + (kc * 2 + h32) * 256 + lq * 8);
      st = mfma32(kf, qf[kc], st);
    }
    __builtin_amdgcn_s_setprio(0);

    // tree max over 16 regs, then cross-half via permlane32_swap
    float red[8];
    #pragma unroll
    for (int j = 0; j < 8; j++) red[j] = fmaxf(st[2 * j], st[2 * j + 1]);
    #pragma unroll
    for (int sj = 4; sj >= 1; sj >>= 1)
      #pragma unroll
      for (int j = 0; j < sj; j++) red[j] = fmaxf(red[j], red[j + sj]);
    float tm = red[0];
    {
      unsigned x = __builtin_bit_cast(unsigned, tm);
      unsigned y = x;
      plane32swap(x, y);   // x={lo,lo}, y={hi,hi}
      tm = fmaxf(__builtin_bit_cast(float, x), __builtin_bit_cast(float, y));
    }

    // defer-max: rescale only if some column grew its max by > 8 (log2)
    if (!__all(tm - m <= 8.0f)) {
      float mn = fmaxf(m, tm);
      float alpha = exp2f(m - mn);
      m = mn;
      l *= alpha;
      #pragma unroll
      for (int r = 0; r < 16; r++) { oa[0][r] *= alpha; oa[1][r] *= alpha; }
    }

    // p = exp2(st - m); per-half sum (halves merged at epilogue)
    #pragma unroll
    for (int r = 0; r < 16; r++) st[r] = exp2f(st[r] - m);
    float sred[8];
    #pragma unroll
    for (int j = 0; j < 8; j++) sred[j] = st[2 * j] + st[2 * j + 1];
    #pragma unroll
    for (int sj = 4; sj >= 1; sj >>= 1)
      #pragma unroll
      for (int j = 0; j < sj; j++) sred[j] += sred[j + sj];
    l += sred[0];

    // P^T -> B-fragments: pack then permlane32_swap pairs
    unsigned w[8];
    #pragma unroll
    for (int j = 0; j < 8; j++) w[j] = pack2(st[2 * j], st[2 * j + 1]);
    plane32swap(w[0], w[2]);
    plane32swap(w[1], w[3]);
    plane32swap(w[4], w[6]);
    plane32swap(w[5], w[7]);
    union { unsigned u[4]; bf16x8 v; } ub0, ub1;
    ub0.u[0] = w[0]; ub0.u[1] = w[1]; ub0.u[2] = w[2]; ub0.u[3] = w[3];
    ub1.u[0] = w[4]; ub1.u[1] = w[5]; ub1.u[2] = w[6]; ub1.u[3] = w[7];

    // O^T += Vt . P^T  (V fragments from LDS)
    #pragma unroll
    for (int db = 0; db < 2; db++) {
      bf16x8 v0 = *reinterpret_cast<const bf16x8*>(vb + (0 + h32) * 512 + (db * 32 + lq) * 8);
      bf16x8 v1 = *reinterpret_cast<const bf16x8*>(vb + (2 + h32) * 512 + (db * 32 + lq) * 8);
      __builtin_amdgcn_s_setprio(1);
      oa[db] = mfma32(v0, ub0.v, oa[db]);
      oa[db] = mfma32(v1, ub1.v, oa[db]);
      __builtin_amdgcn_s_setprio(0);
    }

    c += 1; if (c >= 3) c -= 3;
  }

  // drain wrap-stage loads, then everyone past loop before union reuse
  asm volatile("s_waitcnt vmcnt(0)" ::: "memory");
  __syncthreads();

  // ---- in-block merge of the 2 f-stream partials per q-tile ----
  #pragma unroll
  for (int db = 0; db < 2; db++)
    #pragma unroll
    for (int r = 0; r < 16; r++) {
      int d = db * 32 + (r & 3) + 8 * (r >> 2) + 4 * h32;
      lds.mg.o[wv][d][lq] = oa[db][r];
    }
  if (lane < 32) lds.mg.mm[wv][lq] = m;
  lds.mg.lh[wv][h32][lq] = l;
  __syncthreads();

  int tid = threadIdx.x;
  #pragma unroll
  for (int j = 0; j < 16; j++) {
    int e = tid + j * 256;            // 4096 = 2 tiles x 32 q x 64 d
    int ti = e >> 11;
    int q = (e >> 6) & 31;
    int d = e & 63;
    int wA = ti, wB = ti + 2;
    float mA = lds.mg.mm[wA][q], mB = lds.mg.mm[wB][q];
    float M = fmaxf(mA, mB);
    float eA = exp2f(mA - M), eB = exp2f(mB - M);
    float L = (lds.mg.lh[wA][0][q] + lds.mg.lh[wA][1][q]) * eA
            + (lds.mg.lh[wB][0][q] + lds.mg.lh[wB][1][q]) * eB;
    float O = lds.mg.o[wA][d][q] * eA + lds.mg.o[wB][d][q] * eB;
    int row = qb * 64 + ti * 32 + q;
    size_t ridx = ((size_t)FQ * 8 + bh) * 4096 + row;
    Opart[ridx * 64 + d] = (bf16)O;           // unnormalized partial
    if (d == 0) MLp[ridx] = make_float2(M, L);
  }
}

// ---------------------------------------------------------------------------
// Combine the 2 cross-block f-half partials -> AO[b][t][h*64+d] (bf16).
// ---------------------------------------------------------------------------
__global__ __launch_bounds__(256)
void merge_kernel(const bf16* __restrict__ Op, const float2* __restrict__ MLp,
                  bf16* __restrict__ AO)
{
  int e = blockIdx.x * 256 + threadIdx.x;   // 0..262143
  int rid = e >> 3, dc = e & 7;
  int bh = rid >> 12, row = rid & 4095;
  float2 ml0 = MLp[(size_t)bh * 4096 + row];
  float2 ml1 = MLp[(size_t)(8 + bh) * 4096 + row];
  float M = fmaxf(ml0.x, ml1.x);
  float s0 = exp2f(ml0.x - M), s1 = exp2f(ml1.x - M);
  float inv = 1.f / (ml0.y * s0 + ml1.y * s1);
  s0 *= inv; s1 *= inv;
  bf16x8 a = *reinterpret_cast<const bf16x8*>(Op + ((size_t)bh * 4096 + row) * 64 + dc * 8);
  bf16x8 b = *reinterpret_cast<const bf16x8*>(Op + ((size_t)(8 + bh) * 4096 + row) * 64 + dc * 8);
  bf16x8 o;
  #pragma unroll
  for (int i = 0; i < 8; i++)
    o[i] = (bf16)((float)a[i] * s0 + (float)b[i] * s1);
  int b_ = bh >> 2, hh = bh & 3;
  *reinterpret_cast<bf16x8*>(AO + ((size_t)b_ * 4096 + row) * 256 + hh * 64 + dc * 8) = o;
}

// ---------------------------------------------------------------------------
extern "C" void kernel_launch(void* const* d_in, const int* in_sizes, int n_in,
                              void* d_out, int out_size, void* d_ws, size_t ws_size,
                              hipStream_t stream) {
  const float* t   = (const float*)d_in[0];
  const float* f   = (const float*)d_in[1];
  const float* nw  = (const float*)d_in[2];
  const float* wq  = (const float*)d_in[3];
  const float* bq  = (const float*)d_in[4];
  const float* wkv = (const float*)d_in[5];
  const float* bkv = (const float*)d_in[6];
  const float* wp  = (const float*)d_in[7];
  const float* bp  = (const float*)d_in[8];
  float* out = (float*)d_out;

  bf16* ws = (bf16*)d_ws;
  const size_t NTOK = 2097152;        // 2*4096*256
  bf16* tn   = ws;
  bf16* fn   = ws + NTOK;
  bf16* q    = ws + 2 * NTOK;
  bf16* k    = ws + 3 * NTOK;
  bf16* vt   = ws + 4 * NTOK;
  bf16* ao   = ws + 5 * NTOK;
  bf16* wqT  = ws + 6 * NTOK;
  bf16* wkvT = wqT + 65536;
  bf16* wpT  = wkvT + 131072;
  bf16* opart = wpT + 65536;                        // 2*8*4096*64 bf16 = 8 MB
  float2* mlp = (float2*)(opart + (size_t)2 * 8 * 4096 * 64);  // 512 KB

  prep_kernel<<<5120, 256, 0, stream>>>(t, f, nw, wq, wkv, wp, tn, fn, wqT, wkvT, wpT);
  gemm_qkv<<<1536, 256, 0, stream>>>(tn, fn, wqT, wkvT, bq, bkv, q, k, vt);
  attn_kernel<<<1024, 256, 0, stream>>>(q, k, vt, opart, mlp);
  merge_kernel<<<1024, 256, 0, stream>>>(opart, mlp, ao);
  gemm_out<<<512, 256, 0, stream>>>(ao, wpT, bp, tn, out);
}

// Round 9
// 135.613 us; speedup vs baseline: 1.0542x; 1.0542x over previous
//
#include <hip/hip_runtime.h>

typedef __bf16 bf16;
typedef __bf16 bf16x4 __attribute__((ext_vector_type(4)));
typedef __bf16 bf16x8 __attribute__((ext_vector_type(8)));
typedef float f32x2 __attribute__((ext_vector_type(2)));
typedef float f32x4 __attribute__((ext_vector_type(4)));
typedef float f32x16 __attribute__((ext_vector_type(16)));

__device__ __forceinline__ f32x4 mfma16(bf16x8 a, bf16x8 b, f32x4 c) {
  return __builtin_amdgcn_mfma_f32_16x16x32_bf16(a, b, c, 0, 0, 0);
}
__device__ __forceinline__ f32x16 mfma32(bf16x8 a, bf16x8 b, f32x16 c) {
  return __builtin_amdgcn_mfma_f32_32x32x16_bf16(a, b, c, 0, 0, 0);
}

__device__ __forceinline__ unsigned pack2(float lo, float hi) {
  unsigned short a = __builtin_bit_cast(unsigned short, (bf16)lo);
  unsigned short b = __builtin_bit_cast(unsigned short, (bf16)hi);
  return ((unsigned)b << 16) | (unsigned)a;
}

// v_permlane32_swap_b32 a, b:  a' = {a.lo, b.lo}, b' = {a.hi, b.hi}
__device__ __forceinline__ void plane32swap(unsigned& a, unsigned& b) {
  asm volatile("v_permlane32_swap_b32 %0, %1" : "+v"(a), "+v"(b));
}

// packed f32 add: 2 floats per instruction (CDNA VOP3P)
__device__ __forceinline__ f32x2 pk_add(f32x2 a, f32x2 b) {
  f32x2 d;
  asm("v_pk_add_f32 %0, %1, %2" : "=v"(d) : "v"(a), "v"(b));
  return d;
}

typedef __attribute__((address_space(3))) unsigned int lds_u32;
typedef __attribute__((address_space(1))) unsigned int glb_u32;
// async global->LDS, 16B per lane; LDS dest = base + lane*16 (wave-linear)
__device__ __forceinline__ void gld16(const bf16* g, bf16* l) {
  __builtin_amdgcn_global_load_lds((const glb_u32*)g, (lds_u32*)l, 16, 0, 0);
}

// ---------------------------------------------------------------------------
// prep: fused weight transposes (blocks 0..1023) + RMSNorm (blocks 1024..5119)
// ---------------------------------------------------------------------------
__global__ __launch_bounds__(256)
void prep_kernel(const float* __restrict__ t, const float* __restrict__ f,
                 const float* __restrict__ nw,
                 const float* __restrict__ wq, const float* __restrict__ wkv,
                 const float* __restrict__ wp,
                 bf16* __restrict__ tn, bf16* __restrict__ fn,
                 bf16* __restrict__ wqT, bf16* __restrict__ wkvT,
                 bf16* __restrict__ wpT)
{
  int b = blockIdx.x;
  if (b < 1024) {
    int e = b * 256 + threadIdx.x;   // 0..262143
    const float* src; bf16* dst; int N; int idx;
    if (e < 65536)       { src = wq;  dst = wqT;  N = 256; idx = e; }
    else if (e < 196608) { src = wkv; dst = wkvT; N = 512; idx = e - 65536; }
    else                 { src = wp;  dst = wpT;  N = 256; idx = e - 196608; }
    int k = idx & 255;
    int n = idx >> 8;
    dst[idx] = (bf16)src[(size_t)k * N + n];
    return;
  }
  int wave = threadIdx.x >> 6;
  int lane = threadIdx.x & 63;
  int row = (b - 1024) * 4 + wave;           // 0..16383
  const float* src;
  bf16* dst;
  if (row < 8192) {
    src = t + (size_t)row * 256;
    dst = tn + (size_t)row * 256;
  } else {
    int r2 = row - 8192;
    src = f + (size_t)r2 * 256;
    dst = fn + (size_t)r2 * 256;
  }
  float4 v = reinterpret_cast<const float4*>(src)[lane];
  float ss = v.x * v.x + v.y * v.y + v.z * v.z + v.w * v.w;
  #pragma unroll
  for (int m = 1; m < 64; m <<= 1) ss += __shfl_xor(ss, m);
  float nrm = rsqrtf(ss * (1.0f / 256.0f) + 1e-5f);
  float4 wv = reinterpret_cast<const float4*>(nw)[lane];
  bf16x4 o;
  o[0] = (bf16)(v.x * nrm * wv.x);
  o[1] = (bf16)(v.y * nrm * wv.y);
  o[2] = (bf16)(v.z * nrm * wv.z);
  o[3] = (bf16)(v.w * nrm * wv.w);
  *reinterpret_cast<bf16x4*>(dst + lane * 4) = o;
}

// ---------------------------------------------------------------------------
// GEMM body: out[M=8192, N] = A[8192,256](bf16) @ W[256,N] + bias
// ---------------------------------------------------------------------------
template<int MODE>
__device__ __forceinline__
void gemm_body(int bid, const bf16* __restrict__ A, const bf16* __restrict__ Wt,
               const float* __restrict__ bias, bf16* __restrict__ o0,
               bf16* __restrict__ o1, const bf16* __restrict__ resid,
               float* __restrict__ outf, int N)
{
  int wv = threadIdx.x >> 6;
  int lane = threadIdx.x & 63;
  int lr = lane & 15;
  int lk = (lane >> 4) * 8;
  int wm = wv >> 1, wn = wv & 1;
  int nb = N >> 6;
  int bm = bid / nb;
  int bn = bid - bm * nb;
  int row0 = bm * 64 + wm * 32;
  int col0 = bn * 64 + wn * 32;
  const bf16* Ap = A + (size_t)row0 * 256;
  const bf16* Wp = Wt + (size_t)col0 * 256;

  f32x4 acc[2][2] = {};
  #pragma unroll
  for (int k0 = 0; k0 < 256; k0 += 32) {
    bf16x8 a[2], b[2];
    #pragma unroll
    for (int mi = 0; mi < 2; mi++)
      a[mi] = *reinterpret_cast<const bf16x8*>(Ap + (size_t)(mi * 16 + lr) * 256 + k0 + lk);
    #pragma unroll
    for (int ni = 0; ni < 2; ni++)
      b[ni] = *reinterpret_cast<const bf16x8*>(Wp + (size_t)(ni * 16 + lr) * 256 + k0 + lk);
    #pragma unroll
    for (int mi = 0; mi < 2; mi++)
      #pragma unroll
      for (int ni = 0; ni < 2; ni++)
        acc[mi][ni] = mfma16(a[mi], b[ni], acc[mi][ni]);
  }

  int rb = (lane >> 4) * 4;
  #pragma unroll
  for (int mi = 0; mi < 2; mi++) {
    #pragma unroll
    for (int ni = 0; ni < 2; ni++) {
      int col = col0 + ni * 16 + lr;
      float bv = bias[col];
      #pragma unroll
      for (int r = 0; r < 4; r++) {
        int row = row0 + mi * 16 + rb + r;
        float val = acc[mi][ni][r] + bv;
        if (MODE == 0) {
          int b_ = row >> 12, tt = row & 4095;
          int h = col >> 6, d = col & 63;
          o0[(((size_t)(b_ * 4 + h)) * 4096 + tt) * 64 + d] = (bf16)val;
        } else if (MODE == 1) {
          int b_ = row >> 12, ff = row & 4095;
          if (col < 256) {
            int h = col >> 6, d = col & 63;
            o0[(((size_t)(b_ * 4 + h)) * 4096 + ff) * 64 + d] = (bf16)val;
          } else {
            int c = col - 256;
            int h = c >> 6, d = c & 63;
            o1[(((size_t)(b_ * 4 + h)) * 64 + d) * 4096 + ff] = (bf16)val;
          }
        } else {
          size_t idx = (size_t)row * 256 + col;
          outf[idx] = val + (float)resid[idx];
        }
      }
    }
  }
}

// Fused Q-proj + KV-proj: blocks [0,512) do Q, [512,1536) do KV.
__global__ __launch_bounds__(256)
void gemm_qkv(const bf16* __restrict__ tn, const bf16* __restrict__ fn,
              const bf16* __restrict__ wqT, const bf16* __restrict__ wkvT,
              const float* __restrict__ bq, const float* __restrict__ bkv,
              bf16* __restrict__ q, bf16* __restrict__ k, bf16* __restrict__ vt)
{
  if (blockIdx.x < 512)
    gemm_body<0>(blockIdx.x, tn, wqT, bq, q, nullptr, nullptr, nullptr, 256);
  else
    gemm_body<1>(blockIdx.x - 512, fn, wkvT, bkv, k, vt, nullptr, nullptr, 512);
}

// Output projection + bias + residual.
__global__ __launch_bounds__(256)
void gemm_out(const bf16* __restrict__ ao, const bf16* __restrict__ wpT,
              const float* __restrict__ bp, const bf16* __restrict__ resid,
              float* __restrict__ outf)
{
  gemm_body<2>(blockIdx.x, ao, wpT, bp, nullptr, nullptr, resid, outf, 256);
}

// ---------------------------------------------------------------------------
// Flash attention v7: raw-barrier counted-vmcnt pipeline, double-buffered.
// grid = 1024 blocks: bh = blockIdx&7 (XCD affinity), qb = (blockIdx>>3)&63,
// FQ = blockIdx>>9 (f-half, 2048 f each).
// Block: 4 waves = 2 q-tiles (qi) x 2 f-streams (fh, 1024 f each).
// Pipeline: prologue stages tiles 0,1 (8 loads/wave outstanding). Loop:
//   s_waitcnt vmcnt(4)   <- tile t's 4 loads (oldest) done; tile t+1 in flight
//   s_barrier            <- raw (NOT __syncthreads: compiler would add vmcnt(0))
//   compute(t) from buf c
//   s_barrier            <- all waves done reading buf c
//   STAGE(t+2 -> buf c)  <- overwrite-safe; full iteration of latency lead
// Wrap-staging keeps vmcnt counts uniform at the tail.
// Softmax VALU: max via v_max3 nests, sum/sub via v_pk_add_f32, defer-max
// THR=8 (log2 units), permlane32_swap exchanges, setprio around MFMA.
// ---------------------------------------------------------------------------
__global__ __launch_bounds__(256, 4)
void attn_kernel(const bf16* __restrict__ Q, const bf16* __restrict__ K,
                 const bf16* __restrict__ Vt, bf16* __restrict__ Opart,
                 float2* __restrict__ MLp)
{
  int bh = blockIdx.x & 7;
  int qb = (blockIdx.x >> 3) & 63;
  int FQ = blockIdx.x >> 9;
  int wv = threadIdx.x >> 6;
  int fh = wv >> 1;                // f-stream 0..1
  int qi = wv & 1;                 // q-tile 0..1
  int lane = threadIdx.x & 63;
  int lq = lane & 31;
  int h32 = lane >> 5;

  const bf16* Qb = Q + ((size_t)bh * 4096 + qb * 64 + qi * 32) * 64;
  const bf16* Kb = K + (size_t)bh * 4096 * 64;
  const bf16* Vb = Vt + (size_t)bh * 64 * 4096;

  __shared__ union {
    bf16 stage[2][2][4096];        // [fh][buf][ K' 2048 | V' 2048 ]  32 KB
    struct {
      float o[4][64][33];
      float mm[4][32];
      float lh[4][2][32];
    } mg;                          // 35.3 KB (union max)
  } lds;

  const float qs = 0.125f * 1.44269504089f;
  bf16x8 qf[4];
  #pragma unroll
  for (int kc = 0; kc < 4; kc++) {
    qf[kc] = *reinterpret_cast<const bf16x8*>(Qb + (size_t)lq * 64 + kc * 16 + h32 * 8);
    #pragma unroll
    for (int i = 0; i < 8; i++) qf[kc][i] = (bf16)((float)qf[kc][i] * qs);
  }

  f32x16 oa[2] = {};
  float m = -3.0e38f, l = 0.f;

  int fbeg = FQ * 2048 + fh * 1024;

  auto STAGE = [&](int buf, int ft) {
    bf16* sb = &lds.stage[fh][buf][0];
    if (qi == 0) {
      #pragma unroll
      for (int j = 0; j < 4; j++) {
        const bf16* src = Kb + (size_t)(ft + lq) * 64 + (j * 2 + h32) * 8;
        gld16(src, sb + j * 512);              // K': dch-major
      }
    } else {
      #pragma unroll
      for (int j = 0; j < 4; j++) {
        const bf16* src = Vb + (size_t)lane * 4096 + ft + j * 8;
        gld16(src, sb + 2048 + j * 512);       // V': fch-major
      }
    }
  };

  // prologue: stage tiles 0 and 1 -> 8 outstanding gld16 per wave
  STAGE(0, fbeg);
  STAGE(1, fbeg + 32);
  asm volatile("" ::: "memory");

  int c = 0;                                   // buf of tile t (c = t&1)
  for (int t = 0; t < 32; ++t) {
    // tile t's 4 loads are the oldest of 8 outstanding
    asm volatile("s_waitcnt vmcnt(4)" ::: "memory");
    __builtin_amdgcn_s_barrier();              // B1: tile t visible to all
    asm volatile("" ::: "memory");

    const bf16* kb = &lds.stage[fh][c][0];
    const bf16* vb = kb + 2048;

    // S^T (32f x 32q) = K . Q^T   (log2 units)
    f32x16 st = {};
    __builtin_amdgcn_s_setprio(1);
    #pragma unroll
    for (int kc = 0; kc < 4; kc++) {
      bf16x8 kf = *reinterpret_cast<const bf16x8*>(kb + (kc * 2 + h32) * 256 + lq * 8);
      st = mfma32(kf, qf[kc], st);
    }
    __builtin_amdgcn_s_setprio(0);

    // tile max: nested triples -> v_max3_f32 (8 ops), then cross-half
    float m0 = fmaxf(fmaxf(st[0], st[1]), st[2]);
    float m1 = fmaxf(fmaxf(st[3], st[4]), st[5]);
    float m2 = fmaxf(fmaxf(st[6], st[7]), st[8]);
    float m3 = fmaxf(fmaxf(st[9], st[10]), st[11]);
    float m4 = fmaxf(fmaxf(st[12], st[13]), st[14]);
    float tm = fmaxf(fmaxf(fmaxf(m0, m1), m2), fmaxf(fmaxf(m3, m4), st[15]));
    {
      unsigned x = __builtin_bit_cast(unsigned, tm);
      unsigned y = x;
      plane32swap(x, y);   // x={lo,lo}, y={hi,hi}
      tm = fmaxf(__builtin_bit_cast(float, x), __builtin_bit_cast(float, y));
    }

    // defer-max: rescale only if some column grew its max by > 8 (log2)
    if (!__all(tm - m <= 8.0f)) {
      float mn = fmaxf(m, tm);
      float alpha = exp2f(m - mn);
      m = mn;
      l *= alpha;
      #pragma unroll
      for (int r = 0; r < 16; r++) { oa[0][r] *= alpha; oa[1][r] *= alpha; }
    }

    // p = exp2(st - m): packed subtract, scalar exp2, packed sum tree
    union { f32x16 v; f32x2 p[8]; float s[16]; } u;
    u.v = st;
    f32x2 mneg = {-m, -m};
    #pragma unroll
    for (int j = 0; j < 8; j++) u.p[j] = pk_add(u.p[j], mneg);
    #pragma unroll
    for (int r = 0; r < 16; r++) u.s[r] = exp2f(u.s[r]);
    f32x2 a0 = pk_add(u.p[0], u.p[1]);
    f32x2 a1 = pk_add(u.p[2], u.p[3]);
    f32x2 a2 = pk_add(u.p[4], u.p[5]);
    f32x2 a3 = pk_add(u.p[6], u.p[7]);
    a0 = pk_add(a0, a1);
    a2 = pk_add(a2, a3);
    a0 = pk_add(a0, a2);
    l += a0[0] + a0[1];

    // P^T -> B-fragments: pack then permlane32_swap pairs
    unsigned w[8];
    #pragma unroll
    for (int j = 0; j < 8; j++) w[j] = pack2(u.s[2 * j], u.s[2 * j + 1]);
    plane32swap(w[0], w[2]);
    plane32swap(w[1], w[3]);
    plane32swap(w[4], w[6]);
    plane32swap(w[5], w[7]);
    union { unsigned u4[4]; bf16x8 v; } ub0, ub1;
    ub0.u4[0] = w[0]; ub0.u4[1] = w[1]; ub0.u4[2] = w[2]; ub0.u4[3] = w[3];
    ub1.u4[0] = w[4]; ub1.u4[1] = w[5]; ub1.u4[2] = w[6]; ub1.u4[3] = w[7];

    // O^T += Vt . P^T  (V fragments from LDS)
    #pragma unroll
    for (int db = 0; db < 2; db++) {
      bf16x8 v0 = *reinterpret_cast<const bf16x8*>(vb + (0 + h32) * 512 + (db * 32 + lq) * 8);
      bf16x8 v1 = *reinterpret_cast<const bf16x8*>(vb + (2 + h32) * 512 + (db * 32 + lq) * 8);
      __builtin_amdgcn_s_setprio(1);
      oa[db] = mfma32(v0, ub0.v, oa[db]);
      oa[db] = mfma32(v1, ub1.v, oa[db]);
      __builtin_amdgcn_s_setprio(0);
    }

    asm volatile("" ::: "memory");
    __builtin_amdgcn_s_barrier();              // B2: buf c fully consumed
    asm volatile("" ::: "memory");

    // stage tile t+2 into buf c (wrap keeps vmcnt uniform; wraps unused)
    int tw = t + 2; if (tw >= 32) tw -= 32;
    STAGE(c, fbeg + tw * 32);
    asm volatile("" ::: "memory");

    c ^= 1;
  }

  // drain all staging loads, full sync before union reuse
  asm volatile("s_waitcnt vmcnt(0)" ::: "memory");
  __syncthreads();

  // ---- in-block merge of the 2 f-stream partials per q-tile ----
  #pragma unroll
  for (int db = 0; db < 2; db++)
    #pragma unroll
    for (int r = 0; r < 16; r++) {
      int d = db * 32 + (r & 3) + 8 * (r >> 2) + 4 * h32;
      lds.mg.o[wv][d][lq] = oa[db][r];
    }
  if (lane < 32) lds.mg.mm[wv][lq] = m;
  lds.mg.lh[wv][h32][lq] = l;
  __syncthreads();

  int tid = threadIdx.x;
  #pragma unroll
  for (int j = 0; j < 16; j++) {
    int e = tid + j * 256;            // 4096 = 2 tiles x 32 q x 64 d
    int ti = e >> 11;
    int q = (e >> 6) & 31;
    int d = e & 63;
    int wA = ti, wB = ti + 2;
    float mA = lds.mg.mm[wA][q], mB = lds.mg.mm[wB][q];
    float M = fmaxf(mA, mB);
    float eA = exp2f(mA - M), eB = exp2f(mB - M);
    float L = (lds.mg.lh[wA][0][q] + lds.mg.lh[wA][1][q]) * eA
            + (lds.mg.lh[wB][0][q] + lds.mg.lh[wB][1][q]) * eB;
    float O = lds.mg.o[wA][d][q] * eA + lds.mg.o[wB][d][q] * eB;
    int row = qb * 64 + ti * 32 + q;
    size_t ridx = ((size_t)FQ * 8 + bh) * 4096 + row;
    Opart[ridx * 64 + d] = (bf16)O;           // unnormalized partial
    if (d == 0) MLp[ridx] = make_float2(M, L);
  }
}

// ---------------------------------------------------------------------------
// Combine the 2 cross-block f-half partials -> AO[b][t][h*64+d] (bf16).
// ---------------------------------------------------------------------------
__global__ __launch_bounds__(256)
void merge_kernel(const bf16* __restrict__ Op, const float2* __restrict__ MLp,
                  bf16* __restrict__ AO)
{
  int e = blockIdx.x * 256 + threadIdx.x;   // 0..262143
  int rid = e >> 3, dc = e & 7;
  int bh = rid >> 12, row = rid & 4095;
  float2 ml0 = MLp[(size_t)bh * 4096 + row];
  float2 ml1 = MLp[(size_t)(8 + bh) * 4096 + row];
  float M = fmaxf(ml0.x, ml1.x);
  float s0 = exp2f(ml0.x - M), s1 = exp2f(ml1.x - M);
  float inv = 1.f / (ml0.y * s0 + ml1.y * s1);
  s0 *= inv; s1 *= inv;
  bf16x8 a = *reinterpret_cast<const bf16x8*>(Op + ((size_t)bh * 4096 + row) * 64 + dc * 8);
  bf16x8 b = *reinterpret_cast<const bf16x8*>(Op + ((size_t)(8 + bh) * 4096 + row) * 64 + dc * 8);
  bf16x8 o;
  #pragma unroll
  for (int i = 0; i < 8; i++)
    o[i] = (bf16)((float)a[i] * s0 + (float)b[i] * s1);
  int b_ = bh >> 2, hh = bh & 3;
  *reinterpret_cast<bf16x8*>(AO + ((size_t)b_ * 4096 + row) * 256 + hh * 64 + dc * 8) = o;
}

// ---------------------------------------------------------------------------
extern "C" void kernel_launch(void* const* d_in, const int* in_sizes, int n_in,
                              void* d_out, int out_size, void* d_ws, size_t ws_size,
                              hipStream_t stream) {
  const float* t   = (const float*)d_in[0];
  const float* f   = (const float*)d_in[1];
  const float* nw  = (const float*)d_in[2];
  const float* wq  = (const float*)d_in[3];
  const float* bq  = (const float*)d_in[4];
  const float* wkv = (const float*)d_in[5];
  const float* bkv = (const float*)d_in[6];
  const float* wp  = (const float*)d_in[7];
  const float* bp  = (const float*)d_in[8];
  float* out = (float*)d_out;

  bf16* ws = (bf16*)d_ws;
  const size_t NTOK = 2097152;        // 2*4096*256
  bf16* tn   = ws;
  bf16* fn   = ws + NTOK;
  bf16* q    = ws + 2 * NTOK;
  bf16* k    = ws + 3 * NTOK;
  bf16* vt   = ws + 4 * NTOK;
  bf16* ao   = ws + 5 * NTOK;
  bf16* wqT  = ws + 6 * NTOK;
  bf16* wkvT = wqT + 65536;
  bf16* wpT  = wkvT + 131072;
  bf16* opart = wpT + 65536;                        // 2*8*4096*64 bf16 = 8 MB
  float2* mlp = (float2*)(opart + (size_t)2 * 8 * 4096 * 64);  // 512 KB

  prep_kernel<<<5120, 256, 0, stream>>>(t, f, nw, wq, wkv, wp, tn, fn, wqT, wkvT, wpT);
  gemm_qkv<<<1536, 256, 0, stream>>>(tn, fn, wqT, wkvT, bq, bkv, q, k, vt);
  attn_kernel<<<1024, 256, 0, stream>>>(q, k, vt, opart, mlp);
  merge_kernel<<<1024, 256, 0, stream>>>(opart, mlp, ao);
  gemm_out<<<512, 256, 0, stream>>>(ao, wpT, bp, tn, out);
}